// Round 2
// baseline (1189.837 us; speedup 1.0000x reference)
//
#include <hip/hip_runtime.h>

// MetaPath2Vec loss, round 2: 8 lanes per walk-row.
//   - each lane holds 32 floats (4x float4) of the 128-dim row, laid out so
//     each dwordx4 instruction covers one 128B cacheline per 8-lane group
//   - 3-step ds_swizzle xor-reduce per dot (vs 5-step bpermute over 32 lanes)
//   - one wave = 8 rows/iteration -> shuffle & transcendental cost per row
//     drops ~6x; fast __expf/__logf (tolerance 0.2, we were at 0.0)

constexpr int DIM = 128;
constexpr int CTX = 7;

template<int IMM>
__device__ __forceinline__ int swz_i(int x) {
    return __builtin_amdgcn_ds_swizzle(x, IMM);
}
template<int IMM>
__device__ __forceinline__ float swz_f(float x) {
    return __int_as_float(__builtin_amdgcn_ds_swizzle(__float_as_int(x), IMM));
}

// sum over the 8-lane group (BitMode xor 1,2,4; and=0x1F)
__device__ __forceinline__ float red8(float p) {
    p += swz_f<0x041F>(p);
    p += swz_f<0x081F>(p);
    p += swz_f<0x101F>(p);
    return p;
}

__global__ void zero_ws_kernel(double* ws) {
    if (threadIdx.x < 2) ws[threadIdx.x] = 0.0;
}

__global__ __launch_bounds__(256) void mp2v_loss_kernel(
    const float* __restrict__ emb,
    const int*   __restrict__ pos_rw,
    const int*   __restrict__ neg_rw,
    double*      __restrict__ ws,
    int pos_rows, int neg_rows)
{
    const int tid     = blockIdx.x * blockDim.x + threadIdx.x;
    const int sub     = threadIdx.x & 7;          // lane within 8-group
    const int group   = tid >> 3;
    const int ngroups = (gridDim.x * blockDim.x) >> 3;
    const int total   = pos_rows + neg_rows;

    double accPos = 0.0, accNeg = 0.0;

    for (int row = group; row < total; row += ngroups) {
        const bool isPos = row < pos_rows;
        const int* rw = isPos ? pos_rw + (size_t)row * CTX
                              : neg_rw + (size_t)(row - pos_rows) * CTX;
        // lanes 0..6 load the 7 indices (lane 7 loads a dup)
        int myidx = rw[sub < CTX ? sub : 0];

        // broadcast index j to all 8 lanes of the group: and=0x18, or=j
        int idx0 = swz_i<(0<<5)|0x18>(myidx);
        int idx1 = swz_i<(1<<5)|0x18>(myidx);
        int idx2 = swz_i<(2<<5)|0x18>(myidx);
        int idx3 = swz_i<(3<<5)|0x18>(myidx);
        int idx4 = swz_i<(4<<5)|0x18>(myidx);
        int idx5 = swz_i<(5<<5)|0x18>(myidx);
        int idx6 = swz_i<(6<<5)|0x18>(myidx);
        int idx[CTX] = {idx0, idx1, idx2, idx3, idx4, idx5, idx6};

        // h (start row): lane's 4 float4s at +0,+32,+64,+96 floats (each
        // instruction = contiguous 128B per 8-lane group = 1 cacheline)
        const float* h0p = emb + (size_t)idx[0] * DIM + sub * 4;
        float4 ha = *(const float4*)(h0p);
        float4 hb = *(const float4*)(h0p + 32);
        float4 hc = *(const float4*)(h0p + 64);
        float4 hd = *(const float4*)(h0p + 96);

        float rowLoss = 0.0f;
        #pragma unroll
        for (int j = 1; j < CTX; ++j) {
            const float* cp = emb + (size_t)idx[j] * DIM + sub * 4;
            float4 ca = *(const float4*)(cp);
            float4 cb = *(const float4*)(cp + 32);
            float4 cc = *(const float4*)(cp + 64);
            float4 cd = *(const float4*)(cp + 96);
            float p = ha.x*ca.x + ha.y*ca.y + ha.z*ca.z + ha.w*ca.w;
            p = fmaf(hb.x, cb.x, fmaf(hb.y, cb.y, fmaf(hb.z, cb.z, fmaf(hb.w, cb.w, p))));
            p = fmaf(hc.x, cc.x, fmaf(hc.y, cc.y, fmaf(hc.z, cc.z, fmaf(hc.w, cc.w, p))));
            p = fmaf(hd.x, cd.x, fmaf(hd.y, cd.y, fmaf(hd.z, cd.z, fmaf(hd.w, cd.w, p))));
            p = red8(p);   // full dot on all 8 lanes

            // stable sigmoid + loss (fast intrinsics; tolerance is 0.2)
            float e = __expf(-fabsf(p));          // in (0,1]
            float r = __frcp_rn(1.0f + e);
            float s = (p >= 0.0f ? 1.0f : e) * r; // sigmoid(p)
            float t = isPos ? (s + 1e-15f) : (1.0f - s + 1e-15f);
            rowLoss -= __logf(t);
        }
        // rowLoss is identical on all 8 lanes; count it once
        float m = (sub == 0) ? rowLoss : 0.0f;
        if (isPos) accPos += (double)m;
        else       accNeg += (double)m;
    }

    // wave-level reduction of the per-lane doubles
    #pragma unroll
    for (int off = 32; off > 0; off >>= 1) {
        accPos += __shfl_down(accPos, off, 64);
        accNeg += __shfl_down(accNeg, off, 64);
    }
    __shared__ double sP[4], sN[4];
    const int wave = threadIdx.x >> 6;
    if ((threadIdx.x & 63) == 0) { sP[wave] = accPos; sN[wave] = accNeg; }
    __syncthreads();
    if (threadIdx.x == 0) {
        atomicAdd(&ws[0], sP[0] + sP[1] + sP[2] + sP[3]);
        atomicAdd(&ws[1], sN[0] + sN[1] + sN[2] + sN[3]);
    }
}

__global__ void finalize_kernel(const double* __restrict__ ws,
                                float* __restrict__ out,
                                double invPosCnt, double invNegCnt)
{
    out[0] = (float)(ws[0] * invPosCnt + ws[1] * invNegCnt);
}

extern "C" void kernel_launch(void* const* d_in, const int* in_sizes, int n_in,
                              void* d_out, int out_size, void* d_ws, size_t ws_size,
                              hipStream_t stream)
{
    const float* emb    = (const float*)d_in[0];
    const int*   pos_rw = (const int*)d_in[1];
    const int*   neg_rw = (const int*)d_in[2];
    float*       out    = (float*)d_out;
    double*      ws     = (double*)d_ws;

    const int pos_rows = in_sizes[1] / CTX;   // 200000
    const int neg_rows = in_sizes[2] / CTX;   // 1000000

    hipLaunchKernelGGL(zero_ws_kernel, dim3(1), dim3(64), 0, stream, ws);

    const int blocks = 4096;
    hipLaunchKernelGGL(mp2v_loss_kernel, dim3(blocks), dim3(256), 0, stream,
                       emb, pos_rw, neg_rw, ws, pos_rows, neg_rows);

    hipLaunchKernelGGL(finalize_kernel, dim3(1), dim3(1), 0, stream,
                       ws, out,
                       1.0 / (6.0 * (double)pos_rows),
                       1.0 / (6.0 * (double)neg_rows));
}

// Round 3
// 1016.684 us; speedup vs baseline: 1.1703x; 1.1703x over previous
//
#include <hip/hip_runtime.h>
#include <hip/hip_fp16.h>

// MetaPath2Vec loss, round 3: fp16 table staged in workspace.
//   R1/R2 both pinned at 685us = 4.3GB logical / 6.27 TB/s combined service
//   ceiling. Fix: halve the bytes. f32->f16 convert (tolerance 0.2, fp16 dot
//   err ~5e-3), table becomes 256MB = L3-sized, gather traffic 2.15GB.

constexpr int DIM = 128;
constexpr int CTX = 7;

typedef _Float16 half2v __attribute__((ext_vector_type(2)));

template<int IMM>
__device__ __forceinline__ int swz_i(int x) {
    return __builtin_amdgcn_ds_swizzle(x, IMM);
}
template<int IMM>
__device__ __forceinline__ float swz_f(float x) {
    return __int_as_float(__builtin_amdgcn_ds_swizzle(__float_as_int(x), IMM));
}
__device__ __forceinline__ float red8(float p) {
    p += swz_f<0x041F>(p);
    p += swz_f<0x081F>(p);
    p += swz_f<0x101F>(p);
    return p;
}

__device__ __forceinline__ half2v bc_h2(unsigned u) {
    half2v h; __builtin_memcpy(&h, &u, 4); return h;
}

__device__ __forceinline__ float dot8(uint4 a, uint4 b, float p) {
#if __has_builtin(__builtin_amdgcn_fdot2)
    p = __builtin_amdgcn_fdot2(bc_h2(a.x), bc_h2(b.x), p, false);
    p = __builtin_amdgcn_fdot2(bc_h2(a.y), bc_h2(b.y), p, false);
    p = __builtin_amdgcn_fdot2(bc_h2(a.z), bc_h2(b.z), p, false);
    p = __builtin_amdgcn_fdot2(bc_h2(a.w), bc_h2(b.w), p, false);
#else
    const unsigned ua[4] = {a.x, a.y, a.z, a.w};
    const unsigned ub[4] = {b.x, b.y, b.z, b.w};
    #pragma unroll
    for (int i = 0; i < 4; ++i) {
        float2 fa = __half22float2(*(const __half2*)&ua[i]);
        float2 fb = __half22float2(*(const __half2*)&ub[i]);
        p = fmaf(fa.x, fb.x, p);
        p = fmaf(fa.y, fb.y, p);
    }
#endif
    return p;
}

__global__ void zero_ws_kernel(double* ws) {
    if (threadIdx.x < 2) ws[threadIdx.x] = 0.0;
}

__device__ __forceinline__ unsigned pk_f16(float x, float y) {
    __half2 h = __floats2half2_rn(x, y);
    unsigned r; __builtin_memcpy(&r, &h, 4); return r;
}

__global__ __launch_bounds__(256) void convert_kernel(
    const float4* __restrict__ in, uint2* __restrict__ out, int n4)
{
    int i = blockIdx.x * blockDim.x + threadIdx.x;
    const int stride = gridDim.x * blockDim.x;
    for (; i < n4; i += stride) {
        float4 v = in[i];
        out[i] = make_uint2(pk_f16(v.x, v.y), pk_f16(v.z, v.w));
    }
}

// f16 gather kernel: 8 lanes per walk-row; row = 256B = 16 uint4.
__global__ __launch_bounds__(256) void mp2v_loss_f16_kernel(
    const uint4* __restrict__ tab,
    const int*   __restrict__ pos_rw,
    const int*   __restrict__ neg_rw,
    double*      __restrict__ ws,
    int pos_rows, int neg_rows)
{
    const int tid     = blockIdx.x * blockDim.x + threadIdx.x;
    const int sub     = threadIdx.x & 7;
    const int group   = tid >> 3;
    const int ngroups = (gridDim.x * blockDim.x) >> 3;
    const int total   = pos_rows + neg_rows;

    double accPos = 0.0, accNeg = 0.0;

    int row = group;
    int nextIdx = 0;
    if (row < total) {
        const int* rw = (row < pos_rows) ? pos_rw + (size_t)row * CTX
                                         : neg_rw + (size_t)(row - pos_rows) * CTX;
        nextIdx = rw[sub < CTX ? sub : 0];
    }

    for (; row < total; row += ngroups) {
        const bool isPos = row < pos_rows;
        int myidx = nextIdx;
        // prefetch next iteration's indices (breaks idx->load serialization)
        int nrow = row + ngroups;
        if (nrow < total) {
            const int* rw = (nrow < pos_rows) ? pos_rw + (size_t)nrow * CTX
                                              : neg_rw + (size_t)(nrow - pos_rows) * CTX;
            nextIdx = rw[sub < CTX ? sub : 0];
        }

        int idx0 = swz_i<(0<<5)|0x18>(myidx);
        int idx1 = swz_i<(1<<5)|0x18>(myidx);
        int idx2 = swz_i<(2<<5)|0x18>(myidx);
        int idx3 = swz_i<(3<<5)|0x18>(myidx);
        int idx4 = swz_i<(4<<5)|0x18>(myidx);
        int idx5 = swz_i<(5<<5)|0x18>(myidx);
        int idx6 = swz_i<(6<<5)|0x18>(myidx);
        int idx[CTX] = {idx0, idx1, idx2, idx3, idx4, idx5, idx6};

        // h (start row): 16 uint4 per row; lane takes [sub] and [8+sub]
        const uint4* hp = tab + (size_t)idx[0] * 16;
        uint4 h0 = hp[sub];
        uint4 h1 = hp[8 + sub];

        float rowLoss = 0.0f;
        #pragma unroll
        for (int j = 1; j < CTX; ++j) {
            const uint4* cp = tab + (size_t)idx[j] * 16;
            uint4 c0 = cp[sub];
            uint4 c1 = cp[8 + sub];
            float p = dot8(h0, c0, 0.0f);
            p = dot8(h1, c1, p);
            p = red8(p);

            float e = __expf(-fabsf(p));
            float r = __frcp_rn(1.0f + e);
            float s = (p >= 0.0f ? 1.0f : e) * r;
            float t = isPos ? (s + 1e-15f) : (1.0f - s + 1e-15f);
            rowLoss -= __logf(t);
        }
        float m = (sub == 0) ? rowLoss : 0.0f;
        if (isPos) accPos += (double)m;
        else       accNeg += (double)m;
    }

    #pragma unroll
    for (int off = 32; off > 0; off >>= 1) {
        accPos += __shfl_down(accPos, off, 64);
        accNeg += __shfl_down(accNeg, off, 64);
    }
    __shared__ double sP[4], sN[4];
    const int wave = threadIdx.x >> 6;
    if ((threadIdx.x & 63) == 0) { sP[wave] = accPos; sN[wave] = accNeg; }
    __syncthreads();
    if (threadIdx.x == 0) {
        atomicAdd(&ws[0], sP[0] + sP[1] + sP[2] + sP[3]);
        atomicAdd(&ws[1], sN[0] + sN[1] + sN[2] + sN[3]);
    }
}

// ---------- f32 fallback (round-2 kernel), used when ws too small ----------
__global__ __launch_bounds__(256) void mp2v_loss_f32_kernel(
    const float* __restrict__ emb,
    const int*   __restrict__ pos_rw,
    const int*   __restrict__ neg_rw,
    double*      __restrict__ ws,
    int pos_rows, int neg_rows)
{
    const int tid     = blockIdx.x * blockDim.x + threadIdx.x;
    const int sub     = threadIdx.x & 7;
    const int group   = tid >> 3;
    const int ngroups = (gridDim.x * blockDim.x) >> 3;
    const int total   = pos_rows + neg_rows;

    double accPos = 0.0, accNeg = 0.0;

    for (int row = group; row < total; row += ngroups) {
        const bool isPos = row < pos_rows;
        const int* rw = isPos ? pos_rw + (size_t)row * CTX
                              : neg_rw + (size_t)(row - pos_rows) * CTX;
        int myidx = rw[sub < CTX ? sub : 0];

        int idx0 = swz_i<(0<<5)|0x18>(myidx);
        int idx1 = swz_i<(1<<5)|0x18>(myidx);
        int idx2 = swz_i<(2<<5)|0x18>(myidx);
        int idx3 = swz_i<(3<<5)|0x18>(myidx);
        int idx4 = swz_i<(4<<5)|0x18>(myidx);
        int idx5 = swz_i<(5<<5)|0x18>(myidx);
        int idx6 = swz_i<(6<<5)|0x18>(myidx);
        int idx[CTX] = {idx0, idx1, idx2, idx3, idx4, idx5, idx6};

        const float* h0p = emb + (size_t)idx[0] * DIM + sub * 4;
        float4 ha = *(const float4*)(h0p);
        float4 hb = *(const float4*)(h0p + 32);
        float4 hc = *(const float4*)(h0p + 64);
        float4 hd = *(const float4*)(h0p + 96);

        float rowLoss = 0.0f;
        #pragma unroll
        for (int j = 1; j < CTX; ++j) {
            const float* cp = emb + (size_t)idx[j] * DIM + sub * 4;
            float4 ca = *(const float4*)(cp);
            float4 cb = *(const float4*)(cp + 32);
            float4 cc = *(const float4*)(cp + 64);
            float4 cd = *(const float4*)(cp + 96);
            float p = ha.x*ca.x + ha.y*ca.y + ha.z*ca.z + ha.w*ca.w;
            p = fmaf(hb.x, cb.x, fmaf(hb.y, cb.y, fmaf(hb.z, cb.z, fmaf(hb.w, cb.w, p))));
            p = fmaf(hc.x, cc.x, fmaf(hc.y, cc.y, fmaf(hc.z, cc.z, fmaf(hc.w, cc.w, p))));
            p = fmaf(hd.x, cd.x, fmaf(hd.y, cd.y, fmaf(hd.z, cd.z, fmaf(hd.w, cd.w, p))));
            p = red8(p);

            float e = __expf(-fabsf(p));
            float r = __frcp_rn(1.0f + e);
            float s = (p >= 0.0f ? 1.0f : e) * r;
            float t = isPos ? (s + 1e-15f) : (1.0f - s + 1e-15f);
            rowLoss -= __logf(t);
        }
        float m = (sub == 0) ? rowLoss : 0.0f;
        if (isPos) accPos += (double)m;
        else       accNeg += (double)m;
    }

    #pragma unroll
    for (int off = 32; off > 0; off >>= 1) {
        accPos += __shfl_down(accPos, off, 64);
        accNeg += __shfl_down(accNeg, off, 64);
    }
    __shared__ double sP[4], sN[4];
    const int wave = threadIdx.x >> 6;
    if ((threadIdx.x & 63) == 0) { sP[wave] = accPos; sN[wave] = accNeg; }
    __syncthreads();
    if (threadIdx.x == 0) {
        atomicAdd(&ws[0], sP[0] + sP[1] + sP[2] + sP[3]);
        atomicAdd(&ws[1], sN[0] + sN[1] + sN[2] + sN[3]);
    }
}

__global__ void finalize_kernel(const double* __restrict__ ws,
                                float* __restrict__ out,
                                double invPosCnt, double invNegCnt)
{
    out[0] = (float)(ws[0] * invPosCnt + ws[1] * invNegCnt);
}

extern "C" void kernel_launch(void* const* d_in, const int* in_sizes, int n_in,
                              void* d_out, int out_size, void* d_ws, size_t ws_size,
                              hipStream_t stream)
{
    const float* emb    = (const float*)d_in[0];
    const int*   pos_rw = (const int*)d_in[1];
    const int*   neg_rw = (const int*)d_in[2];
    float*       out    = (float*)d_out;
    double*      ws     = (double*)d_ws;

    const int pos_rows = in_sizes[1] / CTX;   // 200000
    const int neg_rows = in_sizes[2] / CTX;   // 1000000
    const int n_emb_elems = in_sizes[0];      // 128,000,128

    const size_t table_bytes = (size_t)n_emb_elems * 2;   // fp16 table
    const size_t need = 256 + table_bytes;

    hipLaunchKernelGGL(zero_ws_kernel, dim3(1), dim3(64), 0, stream, ws);

    const int blocks = 4096;
    if (ws_size >= need) {
        uint2* tab_w = (uint2*)((char*)d_ws + 256);
        hipLaunchKernelGGL(convert_kernel, dim3(4096), dim3(256), 0, stream,
                           (const float4*)emb, tab_w, n_emb_elems / 4);
        hipLaunchKernelGGL(mp2v_loss_f16_kernel, dim3(blocks), dim3(256), 0, stream,
                           (const uint4*)((char*)d_ws + 256), pos_rw, neg_rw, ws,
                           pos_rows, neg_rows);
    } else {
        hipLaunchKernelGGL(mp2v_loss_f32_kernel, dim3(blocks), dim3(256), 0, stream,
                           emb, pos_rw, neg_rw, ws, pos_rows, neg_rows);
    }

    hipLaunchKernelGGL(finalize_kernel, dim3(1), dim3(1), 0, stream,
                       ws, out,
                       1.0 / (6.0 * (double)pos_rows),
                       1.0 / (6.0 * (double)neg_rows));
}